// Round 4
// baseline (218.253 us; speedup 1.0000x reference)
//
#include <hip/hip_runtime.h>
#include <hip/hip_bf16.h>
#include <stdint.h>

typedef __attribute__((ext_vector_type(8))) short short8;
typedef __attribute__((ext_vector_type(4))) float floatx4;

#define M_TOT 8192
#define N_TOT 3072
#define K_TOT 1024

__device__ inline unsigned short f2bf(float f) {
    union { float f; unsigned int ui; } v; v.f = f;
    unsigned int x = v.ui;
    unsigned int r = (x + 0x7fffu + ((x >> 16) & 1u)) >> 16; // RNE
    return (unsigned short)r;
}

__device__ inline void gl2lds16(const void* g, void* l) {
    __builtin_amdgcn_global_load_lds(
        (__attribute__((address_space(1))) void*)g,
        (__attribute__((address_space(3))) void*)l,
        16, 0, 0);
}

// ---------------------------------------------------------------------------
// Kernel 0: fp32 -> bf16 convert (for x). n8 = n/8.  (unchanged)
// ---------------------------------------------------------------------------
__global__ __launch_bounds__(256) void cvt_f32_bf16_kernel(
    const float* __restrict__ in, unsigned short* __restrict__ out, int n8)
{
    int i = blockIdx.x * 256 + threadIdx.x;
    if (i >= n8) return;
    const float4* p = (const float4*)in + (size_t)i * 2;
    float4 a = p[0], b = p[1];
    short8 s;
    s[0] = (short)f2bf(a.x); s[1] = (short)f2bf(a.y);
    s[2] = (short)f2bf(a.z); s[3] = (short)f2bf(a.w);
    s[4] = (short)f2bf(b.x); s[5] = (short)f2bf(b.y);
    s[6] = (short)f2bf(b.z); s[7] = (short)f2bf(b.w);
    *(short8*)(out + (size_t)i * 8) = s;
}

// ---------------------------------------------------------------------------
// Kernel 1: rotate W -> filt (bf16).  (unchanged)
// ---------------------------------------------------------------------------
__global__ __launch_bounds__(256) void rotate_w_kernel(
    const float* __restrict__ W,    // [3072,1024] fp32
    const float* __restrict__ qR,   // [8,128,128] fp32
    const float* __restrict__ kR,
    const float* __restrict__ vR,
    unsigned short* __restrict__ Fout)   // [3072,1024] bf16
{
    __shared__ float Rs[128 * 128]; // 64 KB
    __shared__ float Ws[64 * 132];  // 33 KB (stride-132 padded)

    const int tid = threadIdx.x;
    const int o0 = blockIdx.x * 64;
    const int r = blockIdx.y;

    const float* R = (o0 < 1024) ? qR : (o0 < 2048) ? kR : vR;
    R += (size_t)r * 128 * 128;

#pragma unroll
    for (int i = 0; i < 16; ++i) {
        int idx = (i * 256 + tid) * 4;
        *(float4*)(Rs + idx) = *(const float4*)(R + idx);
    }
#pragma unroll
    for (int i = 0; i < 8; ++i) {
        int idx = (i * 256 + tid) * 4;
        int row = idx >> 7;
        int col = idx & 127;
        *(float4*)(Ws + row * 132 + col) =
            *(const float4*)(W + (size_t)(o0 + row) * K_TOT + r * 128 + col);
    }
    __syncthreads();

    const int jg = (tid & 15) * 8;  // j base (0,8,...,120)
    const int ob = tid >> 4;        // 0..15

    float acc[4][8];
#pragma unroll
    for (int a = 0; a < 4; ++a)
#pragma unroll
        for (int b = 0; b < 8; ++b) acc[a][b] = 0.f;

    for (int i = 0; i < 128; ++i) {
        float4 r0 = *(const float4*)(Rs + i * 128 + jg);
        float4 r1 = *(const float4*)(Rs + i * 128 + jg + 4);
        float rv[8] = {r0.x, r0.y, r0.z, r0.w, r1.x, r1.y, r1.z, r1.w};
#pragma unroll
        for (int oo = 0; oo < 4; ++oo) {
            float wv = Ws[(ob + oo * 16) * 132 + i];
#pragma unroll
            for (int t = 0; t < 8; ++t) acc[oo][t] += wv * rv[t];
        }
    }

#pragma unroll
    for (int oo = 0; oo < 4; ++oo) {
        int o = o0 + ob + oo * 16;
        short8 s;
#pragma unroll
        for (int t = 0; t < 8; ++t) s[t] = (short)f2bf(acc[oo][t]);
        *(short8*)(Fout + (size_t)o * K_TOT + r * 128 + jg) = s;
    }
}

// ---------------------------------------------------------------------------
// Kernel 2: 256x256x64 8-phase GEMM, out = X @ F^T + bias (fp32 out).
// 512 thr = 8 waves (2M x 4N), per-wave 128x64, mfma_f32_16x16x32_bf16.
// LDS 128 KB dynamic: A[2][256][64] bf16 @byte 0, B[2][256][64] @byte 65536.
// T2: 16B-block swizzle cb ^= (row&7) — pre-swizzled global src, linear DMA
//     dest, swizzled ds_read.
// R4 FIX: fragment reads are INLINE-ASM ds_read_b128. R1-R3 used plain-C LDS
//     reads; since global_load_lds is a compiler-visible LDS writer with
//     un-disambiguable (tid-dependent) addresses, SIInsertWaitcnts emitted
//     s_waitcnt vmcnt(0) before every phase's ds_reads -> full prefetch-queue
//     drain 4-8x per K-tile -> counted-vmcnt (T4) dead -> m97-class 72us.
//     Asm reads are invisible to the DMA-alias machinery; waits are now 100%
//     manual: per-phase s_waitcnt lgkmcnt(0) AFTER the barrier (+sched_barrier
//     per rule #18; lgkmcnt does NOT count LDS-DMA), vmcnt(6) once per K-tile.
// Staging rotation (ledger-verified, unchanged):
//     A0={rows 0-63,128-191} read p0/p1 -> staged p2 (kt+2, live buf)
//     A1={64-127,192-255} read p2/p3 -> staged next-tile p0
//     B0={0-127}, B1={128-255} read p0/p1 -> staged p2/p3
// Steady state: 14 loads outstanding at p3; vmcnt(6) retires tile kt+1's 8,
// leaves kt+2's 6 in flight across the tile boundary. Drain only in the two
// peeled final tiles.
// C/D (16x16): col=lane&15, row=(lane>>4)*4+reg  [m89].
// ---------------------------------------------------------------------------
#define GKT 16

__global__ __launch_bounds__(512, 2) void gemm256_kernel(
    const unsigned short* __restrict__ X,  // [8192,1024] bf16
    const unsigned short* __restrict__ F,  // [3072,1024] bf16
    const float* __restrict__ bias,        // [3072] fp32
    float* __restrict__ out)               // [8192,3072] fp32
{
    extern __shared__ unsigned short sm[];

    const int tid = threadIdx.x;
    const int wid = tid >> 6;
    const int l   = tid & 63;
    const int wm  = wid >> 2;   // 0..1
    const int wn  = wid & 3;    // 0..3

    // bijective XCD swizzle: 384 blocks, 384 % 8 == 0
    const int bswz = (blockIdx.x & 7) * 48 + (blockIdx.x >> 3);
    const int m0 = (bswz / 12) * 256;
    const int n0 = (bswz % 12) * 256;

    // ---- staging: each ST_* instr covers 64 rows x 64 cols (8KB), 512thr x 16B
    const int srow = tid >> 3;            // 0..63
    const int scb  = tid & 7;             // dest 16B-block (linear)
    const int sgcb = scb ^ (srow & 7);    // pre-swizzled global col-block
    // (rb below is always a multiple of 8, so (srow+rb)&7 == srow&7)

    const unsigned short* Xs = X + (size_t)(m0 + srow) * K_TOT + sgcb * 8;
    const unsigned short* Fs = F + (size_t)(n0 + srow) * K_TOT + sgcb * 8;
    unsigned short* smA = sm + srow * 64 + scb * 8;
    unsigned short* smB = sm + 32768 + srow * 64 + scb * 8;

#define ST_A(bo, rb, kc) gl2lds16(Xs + (size_t)(rb) * K_TOT + (kc), smA + (bo) + (rb) * 64)
#define ST_B(bo, rb, kc) gl2lds16(Fs + (size_t)(rb) * K_TOT + (kc), smB + (bo) + (rb) * 64)
#define ST_A0(bo, kc) { ST_A(bo, 0, kc);   ST_A(bo, 128, kc); }
#define ST_A1(bo, kc) { ST_A(bo, 64, kc);  ST_A(bo, 192, kc); }
#define ST_B0(bo, kc) { ST_B(bo, 0, kc);   ST_B(bo, 64, kc);  }
#define ST_B1(bo, kc) { ST_B(bo, 128, kc); ST_B(bo, 192, kc); }
#define BAR() __builtin_amdgcn_s_barrier()
#define VM6 asm volatile("s_waitcnt vmcnt(6)")
#define VM0 asm volatile("s_waitcnt vmcnt(0)")
#define VMNONE ((void)0)
// per-phase LDS wait: after barrier, before MFMA (rule #18: sched_barrier)
#define LGKM0() { asm volatile("s_waitcnt lgkmcnt(0)"); \
                  __builtin_amdgcn_sched_barrier(0); }

    // ---- fragment-read byte addresses: swizzled slot = cbl ^ (row&7), row&7=l&7
    const int l15 = l & 15;
    const int s8a = (((l >> 4) + 0) ^ (l & 7)) * 8;   // ks=0 slot (elements)
    const int s8b = (((l >> 4) + 4) ^ (l & 7)) * 8;   // ks=1 slot
    const int aA0 = ((wm * 128 + l15) * 64 + s8a) * 2;          // A ks0 (bytes)
    const int aA1 = ((wm * 128 + l15) * 64 + s8b) * 2;          // A ks1
    const int bA0 = 65536 + ((wn * 64 + l15) * 64 + s8a) * 2;   // B ks0
    const int bA1 = 65536 + ((wn * 64 + l15) * 64 + s8b) * 2;   // B ks1

    floatx4 acc[8][4];
#pragma unroll
    for (int i = 0; i < 8; ++i)
#pragma unroll
        for (int j = 0; j < 4; ++j)
#pragma unroll
            for (int t = 0; t < 4; ++t) acc[i][j][t] = 0.f;

    short8 aF[4];      // current (qm, ks) A frags
    short8 bF0[4];     // B frags ks=0 (persist p0..p2)
    short8 bF1[4];     // B frags ks=1 (persist p1..p3)

// inline-asm b128 reads; frag stride = 1024 elem = 2048 bytes (imm offsets)
#define RD4(D, A) { \
    asm volatile("ds_read_b128 %0, %1"             : "=v"(D[0]) : "v"(A)); \
    asm volatile("ds_read_b128 %0, %1 offset:2048" : "=v"(D[1]) : "v"(A)); \
    asm volatile("ds_read_b128 %0, %1 offset:4096" : "=v"(D[2]) : "v"(A)); \
    asm volatile("ds_read_b128 %0, %1 offset:6144" : "=v"(D[3]) : "v"(A)); }

#define MFMA_Q(QM, BF) { __builtin_amdgcn_s_setprio(1); \
        _Pragma("unroll") for (int mf = 0; mf < 4; ++mf) \
        _Pragma("unroll") for (int nf = 0; nf < 4; ++nf) \
            acc[(QM) * 4 + mf][nf] = __builtin_amdgcn_mfma_f32_16x16x32_bf16( \
                aF[mf], BF[nf], acc[(QM) * 4 + mf][nf], 0, 0, 0); \
        __builtin_amdgcn_s_setprio(0); }

// One K-tile: CO = current buf, NO = next buf (element offsets, literals).
// kc1 = (kt+1)*64 (A1 stage), kc2 = (kt+2)*64 (A0/B0/B1 stage).
// S1: stage A1(NO,kc1); S2: stage A0/B0/B1(CO,kc2); WN: vmcnt at p3.
// QM=1 A reads: +8192 bytes (4 frag rows x 2048B).
#define TILE(CO, NO, kc1, kc2, S1, S2, WN) { \
        /* p0: qm0 ks0 */ \
        RD4(aF, aA0 + (CO) * 2); RD4(bF0, bA0 + (CO) * 2); \
        if (S1) { ST_A1(NO, kc1); } \
        BAR(); LGKM0(); MFMA_Q(0, bF0); BAR(); \
        /* p1: qm0 ks1 */ \
        RD4(aF, aA1 + (CO) * 2); RD4(bF1, bA1 + (CO) * 2); \
        BAR(); LGKM0(); MFMA_Q(0, bF1); BAR(); \
        /* p2: qm1 ks0 */ \
        RD4(aF, aA0 + (CO) * 2 + 8192); \
        if (S2) { ST_A0(CO, kc2); ST_B0(CO, kc2); } \
        BAR(); LGKM0(); MFMA_Q(1, bF0); BAR(); \
        /* p3: qm1 ks1 */ \
        RD4(aF, aA1 + (CO) * 2 + 8192); \
        if (S2) { ST_B1(CO, kc2); } \
        WN; \
        BAR(); LGKM0(); MFMA_Q(1, bF1); BAR(); }

    // ---- prologue: tile0 full (8 loads) + tile1 {A0,B0,B1} (6 loads).
    // vmcnt(6) -> tile0 landed; tile1's A1 is staged at tile0.p0.
    ST_A0(0, 0); ST_A1(0, 0); ST_B0(0, 0); ST_B1(0, 0);
    ST_A0(16384, 64); ST_B0(16384, 64); ST_B1(16384, 64);
    VM6;
    BAR();

    // main: tiles 0..13, 2 per iteration (static buffer offsets)
    for (int kt2 = 0; kt2 < 7; ++kt2) {
        const int k0 = kt2 * 128;
        TILE(0,     16384, k0 + 64,  k0 + 128, 1, 1, VM6);
        TILE(16384, 0,     k0 + 128, k0 + 192, 1, 1, VM6);
    }
    // tile 14: stage A1(tile15) only; drain everything at p3
    TILE(0,     16384, 960, 0, 1, 0, VM0);
    // tile 15: pure compute
    TILE(16384, 0,     0,   0, 0, 0, VMNONE);

    // ---- epilogue: bias + direct stores (4 x 64B segments per instruction)
    float bv[4];
#pragma unroll
    for (int nf = 0; nf < 4; ++nf) bv[nf] = bias[n0 + wn * 64 + nf * 16 + l15];

    const int mrow = m0 + wm * 128 + (l >> 4) * 4;
    const int ncol = n0 + wn * 64 + l15;
#pragma unroll
    for (int mf = 0; mf < 8; ++mf)
#pragma unroll
        for (int nf = 0; nf < 4; ++nf) {
            float* po = out + (size_t)(mrow + mf * 16) * N_TOT + ncol + nf * 16;
#pragma unroll
            for (int r = 0; r < 4; ++r)
                po[(size_t)r * N_TOT] = acc[mf][nf][r] + bv[nf];
        }
}

extern "C" void kernel_launch(void* const* d_in, const int* in_sizes, int n_in,
                              void* d_out, int out_size, void* d_ws, size_t ws_size,
                              hipStream_t stream) {
    const float* attn = (const float*)d_in[0]; // [3072,1024] fp32
    const float* bias = (const float*)d_in[1]; // [3072] fp32
    const float* x    = (const float*)d_in[2]; // [4,2048,1024] fp32
    const float* qR   = (const float*)d_in[3]; // [8,128,128] fp32
    const float* kR   = (const float*)d_in[4];
    const float* vR   = (const float*)d_in[5];

    float* out = (float*)d_out; // [4,2048,3072] fp32

    // ws layout: xb [8192*1024] bf16 (16 MB) | filt [3072*1024] bf16 (6 MB)
    unsigned short* xb   = (unsigned short*)d_ws;
    unsigned short* filt = xb + (size_t)M_TOT * K_TOT;

    static bool attr_set = false;
    if (!attr_set) {
        hipFuncSetAttribute((const void*)gemm256_kernel,
                            hipFuncAttributeMaxDynamicSharedMemorySize, 131072);
        attr_set = true;
    }

    const int n8 = (M_TOT * K_TOT) / 8; // 1,048,576
    cvt_f32_bf16_kernel<<<n8 / 256, 256, 0, stream>>>(x, xb, n8);
    rotate_w_kernel<<<dim3(48, 8), 256, 0, stream>>>(attn, qR, kR, vR, filt);
    gemm256_kernel<<<dim3(384), dim3(512), 131072, stream>>>(xb, filt, bias, out);
}

// Round 5
// 199.880 us; speedup vs baseline: 1.0919x; 1.0919x over previous
//
#include <hip/hip_runtime.h>
#include <hip/hip_bf16.h>
#include <stdint.h>

typedef __attribute__((ext_vector_type(8))) short short8;
typedef __attribute__((ext_vector_type(4))) float floatx4;
typedef __attribute__((ext_vector_type(16))) float floatx16;

#define M_TOT 8192
#define N_TOT 3072
#define K_TOT 1024
#define BM 128
#define BN 128
#define BK 64

__device__ inline unsigned short f2bf(float f) {
    union { float f; unsigned int ui; } v; v.f = f;
    unsigned int x = v.ui;
    unsigned int r = (x + 0x7fffu + ((x >> 16) & 1u)) >> 16; // RNE
    return (unsigned short)r;
}

__device__ inline void gl2lds16(const void* g, void* l) {
    __builtin_amdgcn_global_load_lds(
        (__attribute__((address_space(1))) void*)g,
        (__attribute__((address_space(3))) void*)l,
        16, 0, 0);
}

// ---------------------------------------------------------------------------
// Fused prep kernel: rotate_w (waves 0-3) + x fp32->bf16 cvt (waves 4-7).
// R5: wave-role split fusion. cvt waves touch no LDS and arrive at the
// barrier immediately, so rotate-compute (VALU/LDS-bound) overlaps the cvt's
// HBM streaming on the same CU. Both code bodies are verbatim from the
// proven R0 kernels; only the thread mapping changed.
// Barrier matching: every wave executes exactly one __syncthreads.
// grid (48, 8) x 512 threads; LDS 97 KB -> 1 block/CU.
// ---------------------------------------------------------------------------
__global__ __launch_bounds__(512) void prep_kernel(
    const float* __restrict__ W,    // [3072,1024] fp32
    const float* __restrict__ qR,   // [8,128,128] fp32
    const float* __restrict__ kR,
    const float* __restrict__ vR,
    unsigned short* __restrict__ Fout,   // [3072,1024] bf16
    const float* __restrict__ xin,       // [8192,1024] fp32
    unsigned short* __restrict__ xb,     // [8192,1024] bf16
    int n8)                              // 1048576 groups of 8
{
    __shared__ float Rs[128 * 128]; // 64 KB
    __shared__ float Ws[64 * 132];  // 33 KB (stride-132 padded)

    const int tid = threadIdx.x;    // 0..511
    const int o0 = blockIdx.x * 64;
    const int r = blockIdx.y;

    if (tid < 256) {
        // ---------------- rotate waves (0-3): stage -> barrier -> compute ---
        const float* R = (o0 < 1024) ? qR : (o0 < 2048) ? kR : vR;
        R += (size_t)r * 128 * 128;

#pragma unroll
        for (int i = 0; i < 16; ++i) {
            int idx = (i * 256 + tid) * 4;
            *(float4*)(Rs + idx) = *(const float4*)(R + idx);
        }
#pragma unroll
        for (int i = 0; i < 8; ++i) {
            int idx = (i * 256 + tid) * 4;
            int row = idx >> 7;
            int col = idx & 127;
            *(float4*)(Ws + row * 132 + col) =
                *(const float4*)(W + (size_t)(o0 + row) * K_TOT + r * 128 + col);
        }
        __syncthreads();

        const int jg = (tid & 15) * 8;  // j base (0,8,...,120)
        const int ob = tid >> 4;        // 0..15

        float acc[4][8];
#pragma unroll
        for (int a = 0; a < 4; ++a)
#pragma unroll
            for (int b = 0; b < 8; ++b) acc[a][b] = 0.f;

        for (int i = 0; i < 128; ++i) {
            float4 r0 = *(const float4*)(Rs + i * 128 + jg);
            float4 r1 = *(const float4*)(Rs + i * 128 + jg + 4);
            float rv[8] = {r0.x, r0.y, r0.z, r0.w, r1.x, r1.y, r1.z, r1.w};
#pragma unroll
            for (int oo = 0; oo < 4; ++oo) {
                float wv = Ws[(ob + oo * 16) * 132 + i];
#pragma unroll
                for (int t = 0; t < 8; ++t) acc[oo][t] += wv * rv[t];
            }
        }

#pragma unroll
        for (int oo = 0; oo < 4; ++oo) {
            int o = o0 + ob + oo * 16;
            short8 s;
#pragma unroll
            for (int t = 0; t < 8; ++t) s[t] = (short)f2bf(acc[oo][t]);
            *(short8*)(Fout + (size_t)o * K_TOT + r * 128 + jg) = s;
        }
    } else {
        // ---------------- cvt waves (4-7): barrier (immediate) -> stream ----
        __syncthreads();
        const int gbid = r * 48 + blockIdx.x;          // 0..383
        int g = gbid * 256 + (tid - 256);              // 0..98303
        for (; g < n8; g += 384 * 256) {
            const float4* p = (const float4*)xin + (size_t)g * 2;
            float4 a = p[0], b = p[1];
            short8 s;
            s[0] = (short)f2bf(a.x); s[1] = (short)f2bf(a.y);
            s[2] = (short)f2bf(a.z); s[3] = (short)f2bf(a.w);
            s[4] = (short)f2bf(b.x); s[5] = (short)f2bf(b.y);
            s[6] = (short)f2bf(b.z); s[7] = (short)f2bf(b.w);
            *(short8*)(xb + (size_t)g * 8) = s;
        }
    }
}

// ---------------------------------------------------------------------------
// GEMM: exact revert to the proven R0 kernel (70 us, MfmaUtil 31%).
// out[m,n] = sum_k X[m,k]*F[n,k] + bias[n]   (bias/out fp32)
// 128x128 tile, BK=64, 4 waves (2x2); per wave 2x2 tiles of 32x32x16 MFMA.
// Latin-square LDS swizzle: LDS[row][cg] = G[row][cg ^ f(row)],
//   f(row) = (row&7) ^ 2*((row>>3)&3)
// C/D (32x32): col=lane&31, row=(reg&3)+8*(reg>>2)+4*(lane>>5) [m74/m101].
// Epilogue bounced through LDS for full-line float4 global stores (no RFO).
// ---------------------------------------------------------------------------
__global__ void gemm_bt_kernel(
    const unsigned short* __restrict__ X,  // [8192,1024] bf16 (ws)
    const unsigned short* __restrict__ F,  // [3072,1024] bf16 (ws)
    const float* __restrict__ bias,        // [3072] fp32
    float* __restrict__ out)               // [8192,3072] fp32
{
    __shared__ __align__(16) unsigned char smem[2 * BM * BK * sizeof(unsigned short)];
    unsigned short* As = (unsigned short*)smem;            // 16 KB
    unsigned short* Bs = As + BM * BK;                     // 16 KB
    float* Cs = (float*)smem;                              // 32 KB = 64x128 fp32

    const int tid = threadIdx.x;
    const int wave = tid >> 6;
    const int lane = tid & 63;
    const int m0 = blockIdx.x * BM;
    const int n0 = blockIdx.y * BN;

    const int wm = wave >> 1; // 0..1
    const int wn = wave & 1;  // 0..1
    const int l31 = lane & 31;
    const int khalf = lane >> 5;

    // staging: per instr p, wave covers 8 rows (lane>>3) x 8 colgroups (lane&7)
    const int srow_lane = lane >> 3;              // 0..7  == row & 7

    floatx16 acc[2][2];
#pragma unroll
    for (int a = 0; a < 2; ++a)
#pragma unroll
        for (int b = 0; b < 2; ++b)
#pragma unroll
            for (int t = 0; t < 16; ++t) acc[a][b][t] = 0.f;

    // fragment-read swizzle term: f(row), row&7 = l31&7, (row>>3)&3 = (l31>>3)&3
    const int fr_read = (l31 & 7) ^ (((l31 >> 3) & 3) << 1);

    for (int k0 = 0; k0 < K_TOT; k0 += BK) {
#pragma unroll
        for (int p = 0; p < 4; ++p) {
            const int rr = (wave * 4 + p) * 8 + srow_lane;
            // f(rr) = srow_lane ^ 2*((wave*4+p)&3)
            const int scg = (lane & 7) ^ srow_lane ^ ((((wave * 4 + p) & 3)) << 1);
            const int scol = scg * 8;
            gl2lds16(X + (size_t)(m0 + rr) * K_TOT + k0 + scol,
                     As + (wave * 4 + p) * 512 + lane * 8);
            gl2lds16(F + (size_t)(n0 + rr) * K_TOT + k0 + scol,
                     Bs + (wave * 4 + p) * 512 + lane * 8);
        }
        __syncthreads();

#pragma unroll
        for (int ks = 0; ks < 4; ++ks) {
            const int fcg = ((ks * 2 + khalf) ^ fr_read) * 8;
            short8 a[2], b[2];
#pragma unroll
            for (int mi = 0; mi < 2; ++mi)
                a[mi] = *(const short8*)(As + (wm * 64 + mi * 32 + l31) * BK + fcg);
#pragma unroll
            for (int ni = 0; ni < 2; ++ni)
                b[ni] = *(const short8*)(Bs + (wn * 64 + ni * 32 + l31) * BK + fcg);
#pragma unroll
            for (int mi = 0; mi < 2; ++mi)
#pragma unroll
                for (int ni = 0; ni < 2; ++ni)
                    acc[mi][ni] = __builtin_amdgcn_mfma_f32_32x32x16_bf16(
                        a[mi], b[ni], acc[mi][ni], 0, 0, 0);
        }
        __syncthreads();
    }

    // ---- Epilogue via LDS: two 64-row halves, full-line float4 stores ----
    float bv[2];
#pragma unroll
    for (int ni = 0; ni < 2; ++ni)
        bv[ni] = bias[n0 + wn * 64 + ni * 32 + l31];

#pragma unroll
    for (int h = 0; h < 2; ++h) {
        if (wm == h) {
#pragma unroll
            for (int mi = 0; mi < 2; ++mi)
#pragma unroll
                for (int ni = 0; ni < 2; ++ni) {
                    const int col = wn * 64 + ni * 32 + l31;
#pragma unroll
                    for (int reg = 0; reg < 16; ++reg) {
                        const int row = mi * 32 + (reg & 3) + 8 * (reg >> 2) +
                                        4 * khalf;
                        Cs[row * 128 + col] = acc[mi][ni][reg] + bv[ni];
                    }
                }
        }
        __syncthreads();
        // 256 threads store 64 rows x 128 cols fp32: 8 rounds of float4
#pragma unroll
        for (int t = 0; t < 8; ++t) {
            const int idx = t * 256 + tid;       // 0..2047
            const int row = idx >> 5;            // 32 float4 per row
            const int c4 = (idx & 31) * 4;
            float4 v = *(const float4*)(Cs + row * 128 + c4);
            *(float4*)(out + (size_t)(m0 + h * 64 + row) * N_TOT + n0 + c4) = v;
        }
        __syncthreads();
    }
}

extern "C" void kernel_launch(void* const* d_in, const int* in_sizes, int n_in,
                              void* d_out, int out_size, void* d_ws, size_t ws_size,
                              hipStream_t stream) {
    const float* attn = (const float*)d_in[0]; // [3072,1024] fp32
    const float* bias = (const float*)d_in[1]; // [3072] fp32
    const float* x    = (const float*)d_in[2]; // [4,2048,1024] fp32
    const float* qR   = (const float*)d_in[3]; // [8,128,128] fp32
    const float* kR   = (const float*)d_in[4];
    const float* vR   = (const float*)d_in[5];

    float* out = (float*)d_out; // [4,2048,3072] fp32

    // ws layout: xb [8192*1024] bf16 (16 MB) | filt [3072*1024] bf16 (6 MB)
    unsigned short* xb   = (unsigned short*)d_ws;
    unsigned short* filt = xb + (size_t)M_TOT * K_TOT;

    const int n8 = (M_TOT * K_TOT) / 8; // 1,048,576
    prep_kernel<<<dim3(48, 8), 512, 0, stream>>>(attn, qR, kR, vR, filt,
                                                 x, xb, n8);
    gemm_bt_kernel<<<dim3(M_TOT / BM, N_TOT / BN), 256, 0, stream>>>(
        xb, filt, bias, out);
}